// Round 16
// baseline (59.658 us; speedup 1.0000x reference)
//
#include <hip/hip_runtime.h>
#include <math.h>

#define NCH 256        // number of simplex chunks (grid_ect = 2*NCH = 512)
#define RSL 8          // reduction slices
#define FPS 32768.0f   // fixed-point scale 2^15 for transition sums
#define REPS 4         // MEASUREMENT: repeat ect body 4x to surface in rocprof

// K1: r12's ect, body repeated REPS times (init/accumulate/flush identical
// each rep -> same partial values -> deterministic; memory clobber between
// reps prevents cross-rep hoisting). Purpose: make ect top-1 in the PMC
// table so VALUBusy / LDS_BANK_CONFLICT / FETCH_SIZE / Occupancy identify
// the ~24us mystery stall. ect_true ~= dispatch_dur / 4.
__global__ __launch_bounds__(1024) void ect_kernel(const float* __restrict__ x,
    const float* __restrict__ v, const int* __restrict__ ei,
    const int* __restrict__ face, const int* __restrict__ batch,
    const float* __restrict__ lin, const int* __restrict__ scale_p,
    int* __restrict__ partial, int N, int E, int F, int M, int csz) {
  __shared__ alignas(16) int hist[8192];  // arr*4096 + g*512 + bin*16 + t16
  int tid = threadIdx.x, bid = blockIdx.x;
  int c = bid >> 1, hf = bid & 1;

  int t16 = tid & 15, srow = tid >> 4;    // srow 0..63
  int tt = (hf << 4) + t16;               // global theta
  float v0 = v[tt], v1 = v[32 + tt], v2 = v[64 + tt];
  int start = c * csz;
  int end = min(start + csz, M);

  float scale = (float)scale_p[0];
  float lin0 = lin[0];
  float step = (lin[31] - lin0) * (1.f / 31.f);
  float istep = 1.f / step;
  float Cl = scale * step * 1.44269504088896f;  // log2-slope per bin
  float w = 13.f / (scale * step);              // transition half-width (bins)

  for (int rep = 0; rep < REPS; ++rep) {
    asm volatile("" ::: "memory");
#pragma unroll
    for (int i = 0; i < 2; ++i)
      ((int4*)hist)[tid + 1024 * i] = int4{0, 0, 0, 0};
    __syncthreads();

    auto dot3 = [&](int n) {
      return fmaf(x[3 * n], v0, fmaf(x[3 * n + 1], v1, x[3 * n + 2] * v2));
    };
    auto deposit = [&](float h, int g, int isn) {
      float kf = (h - lin0) * istep;
      int b0 = (int)ceilf(kf - w);
      int b1 = (int)floorf(kf + w);
      int fs = max(b1 + 1, 0);
      int gb = g << 9;
      if (fs <= 31) atomicAdd(&hist[gb + (fs << 4) + t16], isn);
      float q = Cl * kf;
      float fsn = (float)isn;
      int blo = max(b0, 0), bhi = min(b1, 31);
      for (int b = blo; b <= bhi; ++b) {
        float e2 = __builtin_amdgcn_exp2f(fmaf(-Cl, (float)b, q));
        float val = fsn * __builtin_amdgcn_rcpf(1.f + e2);
        atomicAdd(&hist[4096 + gb + (b << 4) + t16], (int)rintf(val * FPS));
      }
    };

    // nodes
    int e0 = min(end, N);
    for (int m = start + srow; m < e0; m += 64)
      deposit(dot3(m), batch[m], 1);
    // edges (max over 2 endpoints, sign -1)
    int s1 = max(start, N), e1 = min(end, N + E);
    for (int m = s1 + srow; m < e1; m += 64) {
      int e = m - N;
      int n0 = ei[e], n1 = ei[E + e];
      deposit(fmaxf(dot3(n0), dot3(n1)), batch[n0], -1);
    }
    // faces (max over 3 vertices, sign +1)
    int s2 = max(start, N + E);
    for (int m = s2 + srow; m < end; m += 64) {
      int f = m - N - E;
      int n0 = face[f], n1 = face[F + f], n2 = face[2 * F + f];
      deposit(fmaxf(fmaxf(dot3(n0), dot3(n1)), dot3(n2)), batch[n0], 1);
    }
    __syncthreads();
    int4* dst = (int4*)(partial + (size_t)bid * 8192);
    const int4* src = (const int4*)hist;
#pragma unroll
    for (int i = 0; i < 2; ++i)
      dst[tid + 1024 * i] = src[tid + 1024 * i];
    __syncthreads();
  }
}

// K2: tree reduce over chunks. 512 blocks: s = bid>>6 (0..7), cg = bid&63;
// cell cid = cg*256+tid; cid = hf*8192 + (arr*4096 + g*512 + bin*16 + t16).
__global__ __launch_bounds__(256) void reduce_kernel(const int* __restrict__ partial,
    int* __restrict__ part2) {
  int tid = threadIdx.x, bid = blockIdx.x;
  int s = bid >> 6, cg = bid & 63;
  int cid = cg * 256 + tid;
  int hf = cid >> 13, j = cid & 8191;
  int sum = 0;
  for (int cc = s; cc < NCH; cc += RSL)
    sum += partial[(size_t)(cc * 2 + hf) * 8192 + j];
  part2[s * 16384 + cid] = sum;
}

// K3: per-graph block (8 x 1024): sum RSL slices, Hillis-Steele prefix of
// markers over bins, add fractional transitions, per-graph max, normalize.
__global__ __launch_bounds__(1024) void fin_kernel(const int* __restrict__ part2,
    float* __restrict__ out) {
  __shared__ float sP[32][33];
  __shared__ float wmax[16];
  int g = blockIdx.x, tid = threadIdx.x;
  int b = tid >> 5, t = tid & 31;
  int hf = t >> 4, t16 = t & 15;
  int jc = (hf << 13) + (g << 9) + (b << 4) + t16;  // marker cell
  int ja = jc + 4096;                               // transition cell
  int sc = 0, sa = 0;
#pragma unroll
  for (int s = 0; s < RSL; ++s) {
    sc += part2[s * 16384 + jc];
    sa += part2[s * 16384 + ja];
  }
  sP[b][t] = (float)sc;
  __syncthreads();
#pragma unroll
  for (int st = 1; st < 32; st <<= 1) {
    float add = (b >= st) ? sP[b - st][t] : 0.f;
    __syncthreads();
    sP[b][t] += add;
    __syncthreads();
  }
  float r = sP[b][t] + (float)sa * (1.f / FPS);
  float m = r;
#pragma unroll
  for (int off = 32; off > 0; off >>= 1) m = fmaxf(m, __shfl_down(m, off));
  if ((tid & 63) == 0) wmax[tid >> 6] = m;
  __syncthreads();
  if (tid == 0) {
    float mm = wmax[0];
#pragma unroll
    for (int ww = 1; ww < 16; ++ww) mm = fmaxf(mm, wmax[ww]);
    wmax[0] = mm;
  }
  __syncthreads();
  out[(size_t)g * 1024 + tid] = r / wmax[0];
}

extern "C" void kernel_launch(void* const* d_in, const int* in_sizes, int n_in,
                              void* d_out, int out_size, void* d_ws, size_t ws_size,
                              hipStream_t stream) {
  const float* x     = (const float*)d_in[0];
  const float* v     = (const float*)d_in[1];
  const float* lin   = (const float*)d_in[2];
  const int*   ei    = (const int*)d_in[3];
  const int*   face  = (const int*)d_in[4];
  const int*   batch = (const int*)d_in[5];
  const int*   scale = (const int*)d_in[6];
  const int N = in_sizes[5];
  const int E = in_sizes[3] / 2;
  const int F = in_sizes[4] / 3;
  const int M = N + E + F;
  const int csz = (M + NCH - 1) / NCH;   // simplices per chunk (~704)

  int* partial = (int*)d_ws;                          // 2*NCH*8192 ints
  int* part2   = partial + (size_t)2 * NCH * 8192;    // RSL*16384 ints

  ect_kernel<<<2 * NCH, 1024, 0, stream>>>(x, v, ei, face, batch, lin, scale,
                                           partial, N, E, F, M, csz);
  reduce_kernel<<<64 * RSL, 256, 0, stream>>>(partial, part2);
  fin_kernel<<<8, 1024, 0, stream>>>(part2, (float*)d_out);
}

// Round 17
// 37.514 us; speedup vs baseline: 1.5903x; 1.5903x over previous
//
#include <hip/hip_runtime.h>
#include <math.h>

#define NCH 256        // number of simplex chunks (grid_ect = 2*NCH = 512)
#define RSL 8          // reduction slices
#define FPS 32768.0f   // fixed-point scale 2^15 for transition sums

typedef int iv4 __attribute__((ext_vector_type(4)));

// K1: raw-order saturation-split ECT (r12 structure). r16 diagnosis: cold
// rep = 27us, hot rep = 8.8us -> production is COLD because each replay's
// partial stream evicts the 2MB of inputs from per-XCD L2. Fixes:
//  (a) warm-sweep: block linearly reads x+batch slice (slice = bid>>3 so
//      each 8-block group covers the slice on all round-robin XCDs);
//  (b) flush uses nontemporal stores (don't pollute L2);
//  (c) r14 single-bin deposit (2w<1 -> <=1 transition bin) trims VALU
//      (hot regime is 62% VALUBusy).
// LDS hist [arr][g][bin][t16] = 32 KB; LDS int atomics only (deterministic).
__global__ __launch_bounds__(1024) void ect_kernel(const float* __restrict__ x,
    const float* __restrict__ v, const int* __restrict__ ei,
    const int* __restrict__ face, const int* __restrict__ batch,
    const float* __restrict__ lin, const int* __restrict__ scale_p,
    int* __restrict__ partial, int N, int E, int F, int M, int csz) {
  __shared__ alignas(16) int hist[8192];  // arr*4096 + g*512 + bin*16 + t16
  int tid = threadIdx.x, bid = blockIdx.x;
  int c = bid >> 1, hf = bid & 1;
#pragma unroll
  for (int i = 0; i < 2; ++i)
    ((int4*)hist)[tid + 1024 * i] = int4{0, 0, 0, 0};

  // ---- warm-sweep: pull this XCD's copy of x and batch into L2 ----
  {
    int slice = bid >> 3;                     // 64 slices
    const float4* xs = (const float4*)x;      // N*3/4 = 22500 float4
    int nx4 = (N * 3) >> 2;
    int per = (nx4 + 63) >> 6;
    int s0 = slice * per, s1 = min(s0 + per, nx4);
    float keepf = 0.f;
    for (int i = s0 + tid; i < s1; i += 1024) {
      float4 t = xs[i];
      keepf += t.x + t.y + t.z + t.w;
    }
    const int4* bs = (const int4*)batch;      // N/4 = 7500 int4
    int nb4 = N >> 2;
    per = (nb4 + 63) >> 6;
    s0 = slice * per; s1 = min(s0 + per, nb4);
    int keepi = 0;
    for (int i = s0 + tid; i < s1; i += 1024) {
      int4 t = bs[i];
      keepi += t.x ^ t.y ^ t.z ^ t.w;
    }
    asm volatile("" :: "v"(keepf), "v"(keepi));  // keep sweep loads live
  }
  __syncthreads();

  int t16 = tid & 15, srow = tid >> 4;    // srow 0..63
  int tt = (hf << 4) + t16;               // global theta
  float v0 = v[tt], v1 = v[32 + tt], v2 = v[64 + tt];
  int start = c * csz;
  int end = min(start + csz, M);

  float scale = (float)scale_p[0];
  float lin0 = lin[0];
  float step = (lin[31] - lin0) * (1.f / 31.f);
  float istep = 1.f / step;
  float Cl = scale * step * 1.44269504088896f;  // log2-slope per bin
  float w = 13.f / (scale * step);              // transition half-width (bins)

  auto dot3 = [&](int n) {
    return fmaf(x[3 * n], v0, fmaf(x[3 * n + 1], v1, x[3 * n + 2] * v2));
  };
  auto deposit = [&](float h, int g, int isn) {
    float kf = (h - lin0) * istep;
    int fs = max((int)floorf(kf + w) + 1, 0);
    int gb = g << 9;
    if (fs <= 31) atomicAdd(&hist[gb + (fs << 4) + t16], isn);
    float bf = rintf(kf);
    float d = kf - bf;
    if (fabsf(d) <= w) {
      int b = (int)bf;
      if ((unsigned)b <= 31u) {
        float e2 = __builtin_amdgcn_exp2f(Cl * d);
        float val = (float)isn * __builtin_amdgcn_rcpf(1.f + e2);
        atomicAdd(&hist[4096 + gb + (b << 4) + t16], (int)rintf(val * FPS));
      }
    }
  };

  // nodes
  int e0 = min(end, N);
  for (int m = start + srow; m < e0; m += 64)
    deposit(dot3(m), batch[m], 1);
  // edges (max over 2 endpoints, sign -1)
  int s1 = max(start, N), e1 = min(end, N + E);
  for (int m = s1 + srow; m < e1; m += 64) {
    int e = m - N;
    int n0 = ei[e], n1 = ei[E + e];
    deposit(fmaxf(dot3(n0), dot3(n1)), batch[n0], -1);
  }
  // faces (max over 3 vertices, sign +1)
  int s2 = max(start, N + E);
  for (int m = s2 + srow; m < end; m += 64) {
    int f = m - N - E;
    int n0 = face[f], n1 = face[F + f], n2 = face[2 * F + f];
    deposit(fmaxf(fmaxf(dot3(n0), dot3(n1)), dot3(n2)), batch[n0], 1);
  }
  __syncthreads();
  // flush: nontemporal int4 stores — don't evict inputs from L2
  iv4* dst = (iv4*)(partial + (size_t)bid * 8192);
  const iv4* src = (const iv4*)hist;
#pragma unroll
  for (int i = 0; i < 2; ++i)
    __builtin_nontemporal_store(src[tid + 1024 * i], &dst[tid + 1024 * i]);
}

// K2: tree reduce over chunks. 512 blocks: s = bid>>6 (0..7), cg = bid&63;
// cell cid = cg*256+tid; cid = hf*8192 + (arr*4096 + g*512 + bin*16 + t16).
// Nontemporal loads: partial is stream-once data, keep L2 for inputs.
__global__ __launch_bounds__(256) void reduce_kernel(const int* __restrict__ partial,
    int* __restrict__ part2) {
  int tid = threadIdx.x, bid = blockIdx.x;
  int s = bid >> 6, cg = bid & 63;
  int cid = cg * 256 + tid;
  int hf = cid >> 13, j = cid & 8191;
  int sum = 0;
  for (int cc = s; cc < NCH; cc += RSL)
    sum += __builtin_nontemporal_load(&partial[(size_t)(cc * 2 + hf) * 8192 + j]);
  part2[s * 16384 + cid] = sum;
}

// K3: per-graph block (8 x 1024): sum RSL slices, Hillis-Steele prefix of
// markers over bins, add fractional transitions, per-graph max, normalize.
__global__ __launch_bounds__(1024) void fin_kernel(const int* __restrict__ part2,
    float* __restrict__ out) {
  __shared__ float sP[32][33];
  __shared__ float wmax[16];
  int g = blockIdx.x, tid = threadIdx.x;
  int b = tid >> 5, t = tid & 31;
  int hf = t >> 4, t16 = t & 15;
  int jc = (hf << 13) + (g << 9) + (b << 4) + t16;  // marker cell
  int ja = jc + 4096;                               // transition cell
  int sc = 0, sa = 0;
#pragma unroll
  for (int s = 0; s < RSL; ++s) {
    sc += part2[s * 16384 + jc];
    sa += part2[s * 16384 + ja];
  }
  sP[b][t] = (float)sc;
  __syncthreads();
#pragma unroll
  for (int st = 1; st < 32; st <<= 1) {
    float add = (b >= st) ? sP[b - st][t] : 0.f;
    __syncthreads();
    sP[b][t] += add;
    __syncthreads();
  }
  float r = sP[b][t] + (float)sa * (1.f / FPS);
  float m = r;
#pragma unroll
  for (int off = 32; off > 0; off >>= 1) m = fmaxf(m, __shfl_down(m, off));
  if ((tid & 63) == 0) wmax[tid >> 6] = m;
  __syncthreads();
  if (tid == 0) {
    float mm = wmax[0];
#pragma unroll
    for (int ww = 1; ww < 16; ++ww) mm = fmaxf(mm, wmax[ww]);
    wmax[0] = mm;
  }
  __syncthreads();
  out[(size_t)g * 1024 + tid] = r / wmax[0];
}

extern "C" void kernel_launch(void* const* d_in, const int* in_sizes, int n_in,
                              void* d_out, int out_size, void* d_ws, size_t ws_size,
                              hipStream_t stream) {
  const float* x     = (const float*)d_in[0];
  const float* v     = (const float*)d_in[1];
  const float* lin   = (const float*)d_in[2];
  const int*   ei    = (const int*)d_in[3];
  const int*   face  = (const int*)d_in[4];
  const int*   batch = (const int*)d_in[5];
  const int*   scale = (const int*)d_in[6];
  const int N = in_sizes[5];
  const int E = in_sizes[3] / 2;
  const int F = in_sizes[4] / 3;
  const int M = N + E + F;
  const int csz = (M + NCH - 1) / NCH;   // simplices per chunk (~704)

  int* partial = (int*)d_ws;                          // 2*NCH*8192 ints
  int* part2   = partial + (size_t)2 * NCH * 8192;    // RSL*16384 ints

  ect_kernel<<<2 * NCH, 1024, 0, stream>>>(x, v, ei, face, batch, lin, scale,
                                           partial, N, E, F, M, csz);
  reduce_kernel<<<64 * RSL, 256, 0, stream>>>(partial, part2);
  fin_kernel<<<8, 1024, 0, stream>>>(part2, (float*)d_out);
}